// Round 1
// baseline (7222.977 us; speedup 1.0000x reference)
//
#include <hip/hip_runtime.h>
#include <hip/hip_bf16.h>

// Problem constants (B=1)
#define T   512
#define D   256
#define H   4
#define NN  8192      // N per head
#define V   256       // vocab
#define EPSF 1e-5f
#define KS  4         // split-K slices for scores GEMM
#define DSPLIT 16     // split-K slices for decoder GEMM
#define BK  32        // k-tile for all GEMMs
#define N_LAYER 6

// ---------------- block-wide sum over 256 threads (4 waves of 64) ----------
__device__ __forceinline__ float blk_sum256(float v, float* red) {
#pragma unroll
    for (int off = 32; off > 0; off >>= 1) v += __shfl_down(v, off, 64);
    int lane = threadIdx.x & 63, w = threadIdx.x >> 6;
    __syncthreads();                 // protect red[] reuse across calls
    if (lane == 0) red[w] = v;
    __syncthreads();
    return red[0] + red[1] + red[2] + red[3];
}

// ---------------- x = LN(embed[idx]) ---------------------------------------
__global__ __launch_bounds__(256) void embed_ln_k(const int* __restrict__ idx,
                                                  const float* __restrict__ embed,
                                                  float* __restrict__ x) {
    __shared__ float red[4];
    int t = blockIdx.x, d = threadIdx.x;
    float e = embed[(size_t)idx[t] * D + d];
    float m = blk_sum256(e, red) * (1.0f / D);
    float df = e - m;
    float vv = blk_sum256(df * df, red) * (1.0f / D);
    x[(size_t)t * D + d] = df * rsqrtf(vv + EPSF);
}

// ---------------- encoder GEMM:  C[T,NN] = A[T,D] @ W_h[D,NN] --------------
// MODE 0: xs = relu(C); qr = rope(xs)  (RoPE cos/sin computed inline)
// MODE 1: ys = relu(C); xs *= ys       (xy in place, xs holds x_sparse)
template <int MODE>
__global__ __launch_bounds__(256) void enc_gemm_k(const float* __restrict__ A,
                                                  const float* __restrict__ W,
                                                  float* __restrict__ xs,
                                                  float* __restrict__ qr,
                                                  int aHeadStride) {
    __shared__ float As[BK][68];   // k-major, pad 68 -> 16B-aligned float4 rows
    __shared__ float Bs[BK][68];
    int h = blockIdx.z;
    int row0 = blockIdx.y * 64, col0 = blockIdx.x * 64;
    const float* Ah = A + (size_t)h * aHeadStride;
    const float* Wh = W + (size_t)h * D * NN;
    int tid = threadIdx.x, tx = tid & 15, ty = tid >> 4;
    float c[4][4] = {};
    for (int k0 = 0; k0 < D; k0 += BK) {
        for (int l = tid; l < 64 * BK; l += 256) {     // A tile (transposed to k-major)
            int kk = l & 31, r = l >> 5;
            As[kk][r] = Ah[(size_t)(row0 + r) * D + k0 + kk];
        }
        for (int l = tid; l < BK * 64; l += 256) {     // W tile
            int cc = l & 63, kk = l >> 6;
            Bs[kk][cc] = Wh[(size_t)(k0 + kk) * NN + col0 + cc];
        }
        __syncthreads();
#pragma unroll
        for (int kk = 0; kk < BK; ++kk) {
            float4 a4 = *(const float4*)&As[kk][ty * 4];
            float4 b4 = *(const float4*)&Bs[kk][tx * 4];
            float a[4] = {a4.x, a4.y, a4.z, a4.w};
            float b[4] = {b4.x, b4.y, b4.z, b4.w};
#pragma unroll
            for (int i = 0; i < 4; ++i)
#pragma unroll
                for (int j = 0; j < 4; ++j) c[i][j] = fmaf(a[i], b[j], c[i][j]);
        }
        __syncthreads();
    }
    // epilogue
#pragma unroll
    for (int i = 0; i < 4; ++i) {
        int t = row0 + ty * 4 + i;
        int n0 = col0 + tx * 4;
        size_t base = ((size_t)h * T + t) * NN + n0;
        float v0 = fmaxf(c[i][0], 0.0f), v1 = fmaxf(c[i][1], 0.0f);
        float v2 = fmaxf(c[i][2], 0.0f), v3 = fmaxf(c[i][3], 0.0f);
        if (MODE == 0) {
            float cs[4], sn[4];
#pragma unroll
            for (int j = 0; j < 4; ++j) {
                int n = n0 + j;
                float q = (float)(n & ~1);                       // quantize(n,2)
                float f = exp2f(q * (-16.0f / (float)NN)) * 0.15915494309189535f;
                float a = fmodf((float)t * f, 1.0f) * 6.283185307179586f;
                cs[j] = cosf(a); sn[j] = sinf(a);
            }
            // qr[2k] = v[2k]*cos - v[2k+1]*sin ; qr[2k+1] = v[2k+1]*cos + v[2k]*sin
            float4 qv = make_float4(v0 * cs[0] - v1 * sn[0],
                                    v1 * cs[1] + v0 * sn[1],
                                    v2 * cs[2] - v3 * sn[2],
                                    v3 * cs[3] + v2 * sn[3]);
            *(float4*)(xs + base) = make_float4(v0, v1, v2, v3);
            *(float4*)(qr + base) = qv;
        } else {
            float4 old = *(float4*)(xs + base);
            *(float4*)(xs + base) = make_float4(old.x * v0, old.y * v1,
                                                old.z * v2, old.w * v3);
        }
    }
}

// ---------------- scores GEMM: spart[ks][h][t][s] = qr_h[t,:] . qr_h[s,:] ---
// only lower-triangular 64x64 tiles (j<=i); strict mask applied later in av_ln
__global__ __launch_bounds__(256) void qq_gemm_k(const float* __restrict__ qr,
                                                 float* __restrict__ spart) {
    __shared__ float As[BK][68];
    __shared__ float Bs[BK][68];
    int p = blockIdx.x;            // 0..35 -> (i,j), j<=i
    int i = 0, acc = 0;
    while (acc + i + 1 <= p) { ++i; acc += i; }
    int j = p - acc;
    int h = blockIdx.y, ks = blockIdx.z;
    const float* Q = qr + (size_t)h * T * NN;
    int row0 = i * 64, col0 = j * 64;
    int kbeg = ks * (NN / KS);
    int tid = threadIdx.x, tx = tid & 15, ty = tid >> 4;
    float c[4][4] = {};
    for (int k0 = kbeg; k0 < kbeg + NN / KS; k0 += BK) {
        for (int l = tid; l < 64 * BK; l += 256) {
            int kk = l & 31, r = l >> 5;
            As[kk][r] = Q[(size_t)(row0 + r) * NN + k0 + kk];
            Bs[kk][r] = Q[(size_t)(col0 + r) * NN + k0 + kk];
        }
        __syncthreads();
#pragma unroll
        for (int kk = 0; kk < BK; ++kk) {
            float4 a4 = *(const float4*)&As[kk][ty * 4];
            float4 b4 = *(const float4*)&Bs[kk][tx * 4];
            float a[4] = {a4.x, a4.y, a4.z, a4.w};
            float b[4] = {b4.x, b4.y, b4.z, b4.w};
#pragma unroll
            for (int ii = 0; ii < 4; ++ii)
#pragma unroll
                for (int jj = 0; jj < 4; ++jj) c[ii][jj] = fmaf(a[ii], b[jj], c[ii][jj]);
        }
        __syncthreads();
    }
    float* outp = spart + (((size_t)ks * H + h) * T) * T;
#pragma unroll
    for (int ii = 0; ii < 4; ++ii) {
        int t = row0 + ty * 4 + ii;
        *(float4*)(outp + (size_t)t * T + col0 + tx * 4) =
            make_float4(c[ii][0], c[ii][1], c[ii][2], c[ii][3]);
    }
}

// ---------------- ykv[h,t,:] = LN( sum_{s<t} scores(t,s) * x[s,:] ) ---------
__global__ __launch_bounds__(256) void av_ln_k(const float* __restrict__ spart,
                                               const float* __restrict__ x,
                                               float* __restrict__ ykv) {
    __shared__ float red[4];
    int t = blockIdx.x, h = blockIdx.y, d = threadIdx.x;
    const float* s0 = spart + ((size_t)h * T + t) * T;
    const size_t st = (size_t)H * T * T;
    float a = 0.0f;
    for (int s = 0; s < t; ++s) {   // strict causal: s < t only
        float w = s0[s] + s0[st + s] + s0[2 * st + s] + s0[3 * st + s];
        a = fmaf(w, x[(size_t)s * D + d], a);
    }
    float m = blk_sum256(a, red) * (1.0f / D);
    float df = a - m;
    float vv = blk_sum256(df * df, red) * (1.0f / D);
    ykv[((size_t)h * T + t) * D + d] = df * rsqrtf(vv + EPSF);
}

// ---------------- decoder GEMM (split-K): ypart[ks] = xy_chunk @ dec_chunk --
__global__ __launch_bounds__(256) void dec_gemm_k(const float* __restrict__ xy,
                                                  const float* __restrict__ dec,
                                                  float* __restrict__ ypart) {
    __shared__ float As[BK][68];
    __shared__ float Bs[BK][68];
    int ks = blockIdx.z;
    int row0 = blockIdx.y * 64, col0 = blockIdx.x * 64;
    const int CHUNK = (H * NN) / DSPLIT;   // 2048, divides NN
    int cbeg = ks * CHUNK;
    int h = cbeg / NN;
    int n0 = cbeg % NN;
    const float* Ah = xy + ((size_t)h * T) * NN + n0;
    int tid = threadIdx.x, tx = tid & 15, ty = tid >> 4;
    float c[4][4] = {};
    for (int k0 = 0; k0 < CHUNK; k0 += BK) {
        for (int l = tid; l < 64 * BK; l += 256) {
            int kk = l & 31, r = l >> 5;
            As[kk][r] = Ah[(size_t)(row0 + r) * NN + k0 + kk];
        }
        for (int l = tid; l < BK * 64; l += 256) {
            int cc = l & 63, kk = l >> 6;
            Bs[kk][cc] = dec[(size_t)(cbeg + k0 + kk) * D + col0 + cc];
        }
        __syncthreads();
#pragma unroll
        for (int kk = 0; kk < BK; ++kk) {
            float4 a4 = *(const float4*)&As[kk][ty * 4];
            float4 b4 = *(const float4*)&Bs[kk][tx * 4];
            float a[4] = {a4.x, a4.y, a4.z, a4.w};
            float b[4] = {b4.x, b4.y, b4.z, b4.w};
#pragma unroll
            for (int ii = 0; ii < 4; ++ii)
#pragma unroll
                for (int jj = 0; jj < 4; ++jj) c[ii][jj] = fmaf(a[ii], b[jj], c[ii][jj]);
        }
        __syncthreads();
    }
#pragma unroll
    for (int ii = 0; ii < 4; ++ii) {
        int t = row0 + ty * 4 + ii;
        *(float4*)(ypart + ((size_t)ks * T + t) * D + col0 + tx * 4) =
            make_float4(c[ii][0], c[ii][1], c[ii][2], c[ii][3]);
    }
}

// ---------------- y = LN(sum ypart); x = LN(x + y) --------------------------
__global__ __launch_bounds__(256) void final_ln_k(const float* __restrict__ ypart,
                                                  float* __restrict__ x) {
    __shared__ float red[4];
    int t = blockIdx.x, d = threadIdx.x;
    float ys = 0.0f;
#pragma unroll
    for (int ks = 0; ks < DSPLIT; ++ks) ys += ypart[((size_t)ks * T + t) * D + d];
    float m = blk_sum256(ys, red) * (1.0f / D);
    float df = ys - m;
    float vv = blk_sum256(df * df, red) * (1.0f / D);
    float yln = df * rsqrtf(vv + EPSF);
    float val = x[(size_t)t * D + d] + yln;
    float m2 = blk_sum256(val, red) * (1.0f / D);
    float df2 = val - m2;
    float v2 = blk_sum256(df2 * df2, red) * (1.0f / D);
    x[(size_t)t * D + d] = df2 * rsqrtf(v2 + EPSF);
}

// ---------------- logits = x @ lm_head --------------------------------------
__global__ __launch_bounds__(256) void logits_k(const float* __restrict__ x,
                                                const float* __restrict__ lm,
                                                float* __restrict__ out) {
    int t = blockIdx.x, v = threadIdx.x;
    float a = 0.0f;
    for (int d = 0; d < D; ++d)
        a = fmaf(x[(size_t)t * D + d], lm[(size_t)d * V + v], a);
    out[(size_t)t * V + v] = a;
}

extern "C" void kernel_launch(void* const* d_in, const int* in_sizes, int n_in,
                              void* d_out, int out_size, void* d_ws, size_t ws_size,
                              hipStream_t stream) {
    const int*   idx       = (const int*)d_in[0];
    const float* embed     = (const float*)d_in[1];
    const float* encoder   = (const float*)d_in[2];
    const float* encoder_v = (const float*)d_in[3];
    const float* decoder   = (const float*)d_in[4];
    const float* lm_head   = (const float*)d_in[5];
    float* out = (float*)d_out;

    // workspace layout (floats) — total 40,501,248 floats ≈ 155 MiB
    float* w = (float*)d_ws;
    float* x     = w; w += (size_t)T * D;            // current x [T,D]
    float* xs    = w; w += (size_t)H * T * NN;       // x_sparse, later xy (in place)
    float* qr    = w; w += (size_t)H * T * NN;       // rope'd x_sparse
    float* spart = w; w += (size_t)KS * H * T * T;   // scores split-K partials
    float* ykv   = w; w += (size_t)H * T * D;        // LN'd attention output
    float* ypart = w; w += (size_t)DSPLIT * T * D;   // decoder split-K partials

    embed_ln_k<<<T, 256, 0, stream>>>(idx, embed, x);

    for (int layer = 0; layer < N_LAYER; ++layer) {
        // xs = relu(x @ enc_h); qr = rope(xs)
        enc_gemm_k<0><<<dim3(NN / 64, T / 64, H), 256, 0, stream>>>(
            x, encoder, xs, qr, 0);
        // scores partials (lower-triangular tiles only), split-K over NN
        qq_gemm_k<<<dim3(36, H, KS), 256, 0, stream>>>(qr, spart);
        // ykv = LN(scores @ x)   (strict causal sum inside)
        av_ln_k<<<dim3(T, H), 256, 0, stream>>>(spart, x, ykv);
        // ys = relu(ykv @ encv_h); xs = xs * ys   (xy in place)
        enc_gemm_k<1><<<dim3(NN / 64, T / 64, H), 256, 0, stream>>>(
            ykv, encoder_v, xs, nullptr, T * D);
        // ypart[ks] = xy_chunk @ decoder_chunk
        dec_gemm_k<<<dim3(D / 64, T / 64, DSPLIT), 256, 0, stream>>>(
            xs, decoder, ypart);
        // y = LN(sum ypart); x = LN(x + y)
        final_ln_k<<<T, 256, 0, stream>>>(ypart, x);
    }

    logits_k<<<T, 256, 0, stream>>>(x, lm_head, out);
}

// Round 2
// 1358.746 us; speedup vs baseline: 5.3159x; 5.3159x over previous
//
#include <hip/hip_runtime.h>
#include <hip/hip_bf16.h>

#define T   512
#define D   256
#define H   4
#define NN  8192
#define V   256
#define EPSF 1e-5f
#define QKS 4          // split-K for scores GEMM
#define DSPLIT 32      // split-K for decoder GEMM
#define N_LAYER 6

typedef __bf16 bf16;
typedef __attribute__((__ext_vector_type__(8))) __bf16 bf16x8;
typedef __attribute__((__ext_vector_type__(4))) float  f32x4;

// ---------------- block-wide sum over 256 threads ---------------------------
__device__ __forceinline__ float blk_sum256(float v, float* red) {
#pragma unroll
    for (int off = 32; off > 0; off >>= 1) v += __shfl_down(v, off, 64);
    int lane = threadIdx.x & 63, w = threadIdx.x >> 6;
    __syncthreads();
    if (lane == 0) red[w] = v;
    __syncthreads();
    return red[0] + red[1] + red[2] + red[3];
}

// ---------------- transpose + f32->bf16 convert (32x32 tiles) ---------------
__global__ __launch_bounds__(256) void tcvt_k(const float* __restrict__ in,
                                              bf16* __restrict__ out, int R, int C) {
    __shared__ float t[32][33];
    size_t hoff = (size_t)blockIdx.z * R * C;
    int c0 = blockIdx.x * 32, r0 = blockIdx.y * 32;
    int x = threadIdx.x & 31, y = threadIdx.x >> 5;
#pragma unroll
    for (int p = 0; p < 4; ++p)
        t[y + 8 * p][x] = in[hoff + (size_t)(r0 + y + 8 * p) * C + c0 + x];
    __syncthreads();
#pragma unroll
    for (int p = 0; p < 4; ++p)
        out[hoff + (size_t)(c0 + y + 8 * p) * R + r0 + x] = (bf16)t[x][y + 8 * p];
}

// ---------------- RoPE cos/sin tables (bf16, [T][NN]) -----------------------
__global__ __launch_bounds__(256) void rope_tab_k(bf16* __restrict__ cosT,
                                                  bf16* __restrict__ sinT) {
    int n = blockIdx.x * 256 + threadIdx.x;
    int t = blockIdx.y;
    float q = (float)(n & ~1);
    float f = exp2f(q * (-16.0f / (float)NN)) * 0.15915494309189535f;
    float u = fmodf((float)t * f, 1.0f);
    float a = u * 6.283185307179586f;
    cosT[(size_t)t * NN + n] = (bf16)cosf(a);
    sinT[(size_t)t * NN + n] = (bf16)sinf(a);
}

// ---------------- x = LN(embed[idx]) (writes f32 + bf16) --------------------
__global__ __launch_bounds__(256) void embed_ln_k(const int* __restrict__ idx,
                                                  const float* __restrict__ embed,
                                                  float* __restrict__ x,
                                                  bf16* __restrict__ xb) {
    __shared__ float red[4];
    int t = blockIdx.x, d = threadIdx.x;
    float e = embed[(size_t)idx[t] * D + d];
    float m = blk_sum256(e, red) * (1.0f / D);
    float df = e - m;
    float vv = blk_sum256(df * df, red) * (1.0f / D);
    float r = df * rsqrtf(vv + EPSF);
    x[(size_t)t * D + d] = r;
    xb[(size_t)t * D + d] = (bf16)r;
}

// ---------------- shared MFMA 128x128 core ----------------------------------
// A staged row-major [m][k], B staged as rows of B^T: [n][k]; both k-contig.
__device__ __forceinline__ void gemm_core(const bf16* __restrict__ Ap, size_t lda,
                                          const bf16* __restrict__ Bp, size_t ldb,
                                          int ksteps,
                                          bf16 (*As)[40], bf16 (*Bs)[40],
                                          f32x4 acc[4][4], int tid) {
    int lane = tid & 63, wid = tid >> 6;
    int wr = (wid >> 1) * 64, wc = (wid & 1) * 64;
    int fr = lane & 15;
    int fk = (lane >> 4) * 8;
    int r0 = tid >> 2;            // 0..63
    int kq = (tid & 3) * 8;
    for (int ks = 0; ks < ksteps; ++ks) {
        const bf16* a = Ap + ks * 32;
        const bf16* b = Bp + ks * 32;
        *(uint4*)&As[r0][kq]      = *(const uint4*)&a[(size_t)r0 * lda + kq];
        *(uint4*)&As[r0 + 64][kq] = *(const uint4*)&a[(size_t)(r0 + 64) * lda + kq];
        *(uint4*)&Bs[r0][kq]      = *(const uint4*)&b[(size_t)r0 * ldb + kq];
        *(uint4*)&Bs[r0 + 64][kq] = *(const uint4*)&b[(size_t)(r0 + 64) * ldb + kq];
        __syncthreads();
        bf16x8 af[4], bfr[4];
#pragma unroll
        for (int i = 0; i < 4; ++i) {
            af[i]  = *(const bf16x8*)&As[wr + i * 16 + fr][fk];
            bfr[i] = *(const bf16x8*)&Bs[wc + i * 16 + fr][fk];
        }
#pragma unroll
        for (int i = 0; i < 4; ++i)
#pragma unroll
            for (int jj = 0; jj < 4; ++jj)
                acc[i][jj] = __builtin_amdgcn_mfma_f32_16x16x32_bf16(
                    af[i], bfr[jj], acc[i][jj], 0, 0, 0);
        __syncthreads();
    }
}

// ---------------- encoder GEMM + relu (+RoPE / +xy product) -----------------
// MODE 0: xs = relu(C); qr = rope(xs).  MODE 1: xs *= relu(C)  (xy in place)
template <int MODE>
__global__ __launch_bounds__(256) void enc_mfma_k(const bf16* __restrict__ A,
                                                  const bf16* __restrict__ Wt,
                                                  bf16* __restrict__ xs,
                                                  bf16* __restrict__ qr,
                                                  const bf16* __restrict__ cosT,
                                                  const bf16* __restrict__ sinT,
                                                  int aHeadStride) {
    __shared__ bf16 As[128][40];
    __shared__ bf16 Bs[128][40];
    int h = blockIdx.z;
    int row0 = blockIdx.y * 128, col0 = blockIdx.x * 128;
    const bf16* Ap = A + (size_t)h * aHeadStride + (size_t)row0 * D;
    const bf16* Bp = Wt + ((size_t)h * NN + col0) * D;
    int tid = threadIdx.x;
    f32x4 acc[4][4];
#pragma unroll
    for (int i = 0; i < 4; ++i)
#pragma unroll
        for (int j = 0; j < 4; ++j) acc[i][j] = f32x4{0.f, 0.f, 0.f, 0.f};
    gemm_core(Ap, D, Bp, D, D / 32, As, Bs, acc, tid);

    int lane = tid & 63, wid = tid >> 6;
    int wr = (wid >> 1) * 64, wc = (wid & 1) * 64;
    int fr = lane & 15, fq = lane >> 4;
#pragma unroll
    for (int mi = 0; mi < 4; ++mi)
#pragma unroll
        for (int ni = 0; ni < 4; ++ni) {
            int n = col0 + wc + ni * 16 + fr;
            int mbase = row0 + wr + mi * 16 + fq * 4;
#pragma unroll
            for (int j = 0; j < 4; ++j) {
                int m = mbase + j;
                size_t base = ((size_t)h * T + m) * NN + n;
                float v = fmaxf((float)acc[mi][ni][j], 0.0f);
                if (MODE == 0) {
                    float p = __shfl_xor(v, 1, 64);   // partner col n^1
                    float cs = (float)cosT[(size_t)m * NN + n];
                    float sn = (float)sinT[(size_t)m * NN + n];
                    float qv = v * cs + ((n & 1) ? p * sn : -p * sn);
                    xs[base] = (bf16)v;
                    qr[base] = (bf16)qv;
                } else {
                    float xo = (float)xs[base];
                    xs[base] = (bf16)(xo * v);
                }
            }
        }
}

// ---------------- scores GEMM: spart[ks][h][t][s] (lower-tri tiles) ---------
__global__ __launch_bounds__(256) void qq_mfma_k(const bf16* __restrict__ qrb,
                                                 float* __restrict__ spart) {
    __shared__ bf16 As[128][40];
    __shared__ bf16 Bs[128][40];
    static const int TI[10] = {0,1,1,2,2,2,3,3,3,3};
    static const int TJ[10] = {0,0,1,0,1,2,0,1,2,3};
    int ti = TI[blockIdx.x], tj = TJ[blockIdx.x];
    int h = blockIdx.y, ks = blockIdx.z;
    const bf16* Q = qrb + (size_t)h * T * NN + (size_t)ks * (NN / QKS);
    const bf16* Ap = Q + (size_t)(ti * 128) * NN;
    const bf16* Bp = Q + (size_t)(tj * 128) * NN;
    int tid = threadIdx.x;
    f32x4 acc[4][4];
#pragma unroll
    for (int i = 0; i < 4; ++i)
#pragma unroll
        for (int j = 0; j < 4; ++j) acc[i][j] = f32x4{0.f, 0.f, 0.f, 0.f};
    gemm_core(Ap, NN, Bp, NN, (NN / QKS) / 32, As, Bs, acc, tid);

    int lane = tid & 63, wid = tid >> 6;
    int wr = (wid >> 1) * 64, wc = (wid & 1) * 64;
    int fr = lane & 15, fq = lane >> 4;
    float* outp = spart + (size_t)(ks * H + h) * T * T;
#pragma unroll
    for (int mi = 0; mi < 4; ++mi)
#pragma unroll
        for (int ni = 0; ni < 4; ++ni) {
            int s = tj * 128 + wc + ni * 16 + fr;
            int mbase = ti * 128 + wr + mi * 16 + fq * 4;
#pragma unroll
            for (int j = 0; j < 4; ++j)
                outp[(size_t)(mbase + j) * T + s] = acc[mi][ni][j];
        }
}

// ---------------- ykv = LN(scores @ x), strict causal, bf16 out -------------
__global__ __launch_bounds__(256) void av_ln_k(const float* __restrict__ spart,
                                               const float* __restrict__ x,
                                               bf16* __restrict__ ykvb) {
    __shared__ float red[4];
    int t = blockIdx.x, h = blockIdx.y, d = threadIdx.x;
    const float* s0 = spart + ((size_t)h * T + t) * T;
    const size_t st = (size_t)H * T * T;
    float a = 0.0f;
#pragma unroll 4
    for (int s = 0; s < t; ++s) {
        float w = s0[s] + s0[st + s] + s0[2 * st + s] + s0[3 * st + s];
        a = fmaf(w, x[(size_t)s * D + d], a);
    }
    float m = blk_sum256(a, red) * (1.0f / D);
    float df = a - m;
    float vv = blk_sum256(df * df, red) * (1.0f / D);
    ykvb[((size_t)h * T + t) * D + d] = (bf16)(df * rsqrtf(vv + EPSF));
}

// ---------------- decoder GEMM (split-K) ------------------------------------
__global__ __launch_bounds__(256) void dec_mfma_k(const bf16* __restrict__ xyb,
                                                  const bf16* __restrict__ decT,
                                                  float* __restrict__ ypart) {
    __shared__ bf16 As[128][40];
    __shared__ bf16 Bs[128][40];
    int ks = blockIdx.z;
    int cbeg = ks * ((H * NN) / DSPLIT);   // 1024-wide slices, within one head
    int h = cbeg >> 13, n0 = cbeg & (NN - 1);
    int row0 = blockIdx.y * 128, col0 = blockIdx.x * 128;
    const bf16* Ap = xyb + ((size_t)h * T + row0) * NN + n0;
    const bf16* Bp = decT + (size_t)col0 * (H * NN) + cbeg;
    int tid = threadIdx.x;
    f32x4 acc[4][4];
#pragma unroll
    for (int i = 0; i < 4; ++i)
#pragma unroll
        for (int j = 0; j < 4; ++j) acc[i][j] = f32x4{0.f, 0.f, 0.f, 0.f};
    gemm_core(Ap, NN, Bp, H * NN, (H * NN / DSPLIT) / 32, As, Bs, acc, tid);

    int lane = tid & 63, wid = tid >> 6;
    int wr = (wid >> 1) * 64, wc = (wid & 1) * 64;
    int fr = lane & 15, fq = lane >> 4;
#pragma unroll
    for (int mi = 0; mi < 4; ++mi)
#pragma unroll
        for (int ni = 0; ni < 4; ++ni) {
            int n = col0 + wc + ni * 16 + fr;
            int mbase = row0 + wr + mi * 16 + fq * 4;
#pragma unroll
            for (int j = 0; j < 4; ++j)
                ypart[((size_t)ks * T + (mbase + j)) * D + n] = acc[mi][ni][j];
        }
}

// ---------------- y = LN(sum ypart); x = LN(x + y); also bf16 copy ----------
__global__ __launch_bounds__(256) void final_ln_k(const float* __restrict__ ypart,
                                                  float* __restrict__ x,
                                                  bf16* __restrict__ xb) {
    __shared__ float red[4];
    int t = blockIdx.x, d = threadIdx.x;
    float ys = 0.0f;
#pragma unroll
    for (int ks = 0; ks < DSPLIT; ++ks) ys += ypart[((size_t)ks * T + t) * D + d];
    float m = blk_sum256(ys, red) * (1.0f / D);
    float df = ys - m;
    float vv = blk_sum256(df * df, red) * (1.0f / D);
    float yln = df * rsqrtf(vv + EPSF);
    float val = x[(size_t)t * D + d] + yln;
    float m2 = blk_sum256(val, red) * (1.0f / D);
    float df2 = val - m2;
    float v2 = blk_sum256(df2 * df2, red) * (1.0f / D);
    float r = df2 * rsqrtf(v2 + EPSF);
    x[(size_t)t * D + d] = r;
    xb[(size_t)t * D + d] = (bf16)r;
}

// ---------------- logits = x @ lm_head (f32) --------------------------------
__global__ __launch_bounds__(256) void logits_k(const float* __restrict__ x,
                                                const float* __restrict__ lm,
                                                float* __restrict__ out) {
    int t = blockIdx.x, v = threadIdx.x;
    float a = 0.0f;
    for (int d = 0; d < D; ++d)
        a = fmaf(x[(size_t)t * D + d], lm[(size_t)d * V + v], a);
    out[(size_t)t * V + v] = a;
}

extern "C" void kernel_launch(void* const* d_in, const int* in_sizes, int n_in,
                              void* d_out, int out_size, void* d_ws, size_t ws_size,
                              hipStream_t stream) {
    const int*   idx       = (const int*)d_in[0];
    const float* embed     = (const float*)d_in[1];
    const float* encoder   = (const float*)d_in[2];
    const float* encoder_v = (const float*)d_in[3];
    const float* decoder   = (const float*)d_in[4];
    const float* lm_head   = (const float*)d_in[5];
    float* out = (float*)d_out;

    // ---- workspace layout (total ≈ 140 MB) ----
    char* W = (char*)d_ws;
    float* x       = (float*)W; W += (size_t)T * D * 4;
    float* scratch = (float*)W; W += (size_t)QKS * H * T * T * 4;  // spart / ypart union (16.78 MB each)
    bf16* xb    = (bf16*)W; W += (size_t)T * D * 2;
    bf16* ykvb  = (bf16*)W; W += (size_t)H * T * D * 2;
    bf16* encT  = (bf16*)W; W += (size_t)H * NN * D * 2;
    bf16* encVT = (bf16*)W; W += (size_t)H * NN * D * 2;
    bf16* decT  = (bf16*)W; W += (size_t)D * H * NN * 2;
    bf16* cosT  = (bf16*)W; W += (size_t)T * NN * 2;
    bf16* sinT  = (bf16*)W; W += (size_t)T * NN * 2;
    bf16* xs    = (bf16*)W; W += (size_t)H * T * NN * 2;
    bf16* qr    = (bf16*)W; W += (size_t)H * T * NN * 2;

    // ---- one-time per launch: weight transpose+convert, RoPE tables ----
    tcvt_k<<<dim3(NN / 32, D / 32, H), 256, 0, stream>>>(encoder, encT, D, NN);
    tcvt_k<<<dim3(NN / 32, D / 32, H), 256, 0, stream>>>(encoder_v, encVT, D, NN);
    tcvt_k<<<dim3(D / 32, (H * NN) / 32, 1), 256, 0, stream>>>(decoder, decT, H * NN, D);
    rope_tab_k<<<dim3(NN / 256, T), 256, 0, stream>>>(cosT, sinT);

    embed_ln_k<<<T, 256, 0, stream>>>(idx, embed, x, xb);

    for (int layer = 0; layer < N_LAYER; ++layer) {
        enc_mfma_k<0><<<dim3(NN / 128, T / 128, H), 256, 0, stream>>>(
            xb, encT, xs, qr, cosT, sinT, 0);
        qq_mfma_k<<<dim3(10, H, QKS), 256, 0, stream>>>(qr, scratch);
        av_ln_k<<<dim3(T, H), 256, 0, stream>>>(scratch, x, ykvb);
        enc_mfma_k<1><<<dim3(NN / 128, T / 128, H), 256, 0, stream>>>(
            ykvb, encVT, xs, nullptr, nullptr, nullptr, T * D);
        dec_mfma_k<<<dim3(D / 128, T / 128, DSPLIT), 256, 0, stream>>>(
            xs, decT, scratch);
        final_ln_k<<<T, 256, 0, stream>>>(scratch, x, xb);
    }

    logits_k<<<T, 256, 0, stream>>>(x, lm_head, out);
}

// Round 3
// 950.451 us; speedup vs baseline: 7.5995x; 1.4296x over previous
//
#include <hip/hip_runtime.h>
#include <hip/hip_bf16.h>

#define T   512
#define D   256
#define H   4
#define NN  8192
#define V   256
#define EPSF 1e-5f
#define QKS 4          // split-K for scores GEMM
#define DSPLIT 32      // split-K for decoder GEMM
#define N_LAYER 6

typedef __bf16 bf16;
typedef __attribute__((__ext_vector_type__(8))) __bf16 bf16x8;
typedef __attribute__((__ext_vector_type__(4))) float  f32x4;

// ---------------- block-wide sum over 256 threads ---------------------------
__device__ __forceinline__ float blk_sum256(float v, float* red) {
#pragma unroll
    for (int off = 32; off > 0; off >>= 1) v += __shfl_down(v, off, 64);
    int lane = threadIdx.x & 63, w = threadIdx.x >> 6;
    __syncthreads();
    if (lane == 0) red[w] = v;
    __syncthreads();
    return red[0] + red[1] + red[2] + red[3];
}

// ---------------- transpose + f32->bf16 convert (32x32 tiles) ---------------
__global__ __launch_bounds__(256) void tcvt_k(const float* __restrict__ in,
                                              bf16* __restrict__ out, int R, int C) {
    __shared__ float t[32][33];
    size_t hoff = (size_t)blockIdx.z * R * C;
    int c0 = blockIdx.x * 32, r0 = blockIdx.y * 32;
    int x = threadIdx.x & 31, y = threadIdx.x >> 5;
#pragma unroll
    for (int p = 0; p < 4; ++p)
        t[y + 8 * p][x] = in[hoff + (size_t)(r0 + y + 8 * p) * C + c0 + x];
    __syncthreads();
#pragma unroll
    for (int p = 0; p < 4; ++p)
        out[hoff + (size_t)(c0 + y + 8 * p) * R + r0 + x] = (bf16)t[x][y + 8 * p];
}

// ---------------- RoPE cos/sin tables (bf16, [T][NN]) -----------------------
__global__ __launch_bounds__(256) void rope_tab_k(bf16* __restrict__ cosT,
                                                  bf16* __restrict__ sinT) {
    int n = blockIdx.x * 256 + threadIdx.x;
    int t = blockIdx.y;
    float q = (float)(n & ~1);
    float f = exp2f(q * (-16.0f / (float)NN)) * 0.15915494309189535f;
    float u = fmodf((float)t * f, 1.0f);
    float a = u * 6.283185307179586f;
    cosT[(size_t)t * NN + n] = (bf16)cosf(a);
    sinT[(size_t)t * NN + n] = (bf16)sinf(a);
}

// ---------------- x = LN(embed[idx]) (writes f32 + bf16 + bf16^T) -----------
__global__ __launch_bounds__(256) void embed_ln_k(const int* __restrict__ idx,
                                                  const float* __restrict__ embed,
                                                  float* __restrict__ x,
                                                  bf16* __restrict__ xb,
                                                  bf16* __restrict__ xbT) {
    __shared__ float red[4];
    int t = blockIdx.x, d = threadIdx.x;
    float e = embed[(size_t)idx[t] * D + d];
    float m = blk_sum256(e, red) * (1.0f / D);
    float df = e - m;
    float vv = blk_sum256(df * df, red) * (1.0f / D);
    float r = df * rsqrtf(vv + EPSF);
    x[(size_t)t * D + d] = r;
    xb[(size_t)t * D + d] = (bf16)r;
    xbT[(size_t)d * T + t] = (bf16)r;
}

// ---------------- shared MFMA 128x128 core ----------------------------------
// A staged row-major [m][k], B staged as rows of B^T: [n][k]; both k-contig.
__device__ __forceinline__ void gemm_core(const bf16* __restrict__ Ap, size_t lda,
                                          const bf16* __restrict__ Bp, size_t ldb,
                                          int ksteps,
                                          bf16 (*As)[40], bf16 (*Bs)[40],
                                          f32x4 acc[4][4], int tid) {
    int lane = tid & 63, wid = tid >> 6;
    int wr = (wid >> 1) * 64, wc = (wid & 1) * 64;
    int fr = lane & 15;
    int fk = (lane >> 4) * 8;
    int r0 = tid >> 2;            // 0..63
    int kq = (tid & 3) * 8;
    for (int ks = 0; ks < ksteps; ++ks) {
        const bf16* a = Ap + ks * 32;
        const bf16* b = Bp + ks * 32;
        *(uint4*)&As[r0][kq]      = *(const uint4*)&a[(size_t)r0 * lda + kq];
        *(uint4*)&As[r0 + 64][kq] = *(const uint4*)&a[(size_t)(r0 + 64) * lda + kq];
        *(uint4*)&Bs[r0][kq]      = *(const uint4*)&b[(size_t)r0 * ldb + kq];
        *(uint4*)&Bs[r0 + 64][kq] = *(const uint4*)&b[(size_t)(r0 + 64) * ldb + kq];
        __syncthreads();
        bf16x8 af[4], bfr[4];
#pragma unroll
        for (int i = 0; i < 4; ++i) {
            af[i]  = *(const bf16x8*)&As[wr + i * 16 + fr][fk];
            bfr[i] = *(const bf16x8*)&Bs[wc + i * 16 + fr][fk];
        }
#pragma unroll
        for (int i = 0; i < 4; ++i)
#pragma unroll
            for (int jj = 0; jj < 4; ++jj)
                acc[i][jj] = __builtin_amdgcn_mfma_f32_16x16x32_bf16(
                    af[i], bfr[jj], acc[i][jj], 0, 0, 0);
        __syncthreads();
    }
}

// ---------------- encoder GEMM + relu (+RoPE / +xy product) -----------------
// MODE 0: xs = relu(C); qr = rope(xs).  MODE 1: xs *= relu(C)  (xy in place)
template <int MODE>
__global__ __launch_bounds__(256) void enc_mfma_k(const bf16* __restrict__ A,
                                                  const bf16* __restrict__ Wt,
                                                  bf16* __restrict__ xs,
                                                  bf16* __restrict__ qr,
                                                  const bf16* __restrict__ cosT,
                                                  const bf16* __restrict__ sinT,
                                                  int aHeadStride) {
    __shared__ bf16 As[128][40];
    __shared__ bf16 Bs[128][40];
    int h = blockIdx.z;
    int row0 = blockIdx.y * 128, col0 = blockIdx.x * 128;
    const bf16* Ap = A + (size_t)h * aHeadStride + (size_t)row0 * D;
    const bf16* Bp = Wt + ((size_t)h * NN + col0) * D;
    int tid = threadIdx.x;
    f32x4 acc[4][4];
#pragma unroll
    for (int i = 0; i < 4; ++i)
#pragma unroll
        for (int j = 0; j < 4; ++j) acc[i][j] = f32x4{0.f, 0.f, 0.f, 0.f};
    gemm_core(Ap, D, Bp, D, D / 32, As, Bs, acc, tid);

    int lane = tid & 63, wid = tid >> 6;
    int wr = (wid >> 1) * 64, wc = (wid & 1) * 64;
    int fr = lane & 15, fq = lane >> 4;
#pragma unroll
    for (int mi = 0; mi < 4; ++mi)
#pragma unroll
        for (int ni = 0; ni < 4; ++ni) {
            int n = col0 + wc + ni * 16 + fr;
            int mbase = row0 + wr + mi * 16 + fq * 4;
#pragma unroll
            for (int j = 0; j < 4; ++j) {
                int m = mbase + j;
                size_t base = ((size_t)h * T + m) * NN + n;
                float v = fmaxf((float)acc[mi][ni][j], 0.0f);
                if (MODE == 0) {
                    float p = __shfl_xor(v, 1, 64);   // partner col n^1
                    float cs = (float)cosT[(size_t)m * NN + n];
                    float sn = (float)sinT[(size_t)m * NN + n];
                    float qv = v * cs + ((n & 1) ? p * sn : -p * sn);
                    xs[base] = (bf16)v;
                    qr[base] = (bf16)qv;
                } else {
                    float xo = (float)xs[base];
                    xs[base] = (bf16)(xo * v);
                }
            }
        }
}

// ---------------- scores GEMM: spart[ks][h][t][s] (lower-tri tiles) ---------
__global__ __launch_bounds__(256) void qq_mfma_k(const bf16* __restrict__ qrb,
                                                 float* __restrict__ spart) {
    __shared__ bf16 As[128][40];
    __shared__ bf16 Bs[128][40];
    static const int TI[10] = {0,1,1,2,2,2,3,3,3,3};
    static const int TJ[10] = {0,0,1,0,1,2,0,1,2,3};
    int ti = TI[blockIdx.x], tj = TJ[blockIdx.x];
    int h = blockIdx.y, ks = blockIdx.z;
    const bf16* Q = qrb + (size_t)h * T * NN + (size_t)ks * (NN / QKS);
    const bf16* Ap = Q + (size_t)(ti * 128) * NN;
    const bf16* Bp = Q + (size_t)(tj * 128) * NN;
    int tid = threadIdx.x;
    f32x4 acc[4][4];
#pragma unroll
    for (int i = 0; i < 4; ++i)
#pragma unroll
        for (int j = 0; j < 4; ++j) acc[i][j] = f32x4{0.f, 0.f, 0.f, 0.f};
    gemm_core(Ap, NN, Bp, NN, (NN / QKS) / 32, As, Bs, acc, tid);

    int lane = tid & 63, wid = tid >> 6;
    int wr = (wid >> 1) * 64, wc = (wid & 1) * 64;
    int fr = lane & 15, fq = lane >> 4;
    float* outp = spart + (size_t)(ks * H + h) * T * T;
#pragma unroll
    for (int mi = 0; mi < 4; ++mi)
#pragma unroll
        for (int ni = 0; ni < 4; ++ni) {
            int s = tj * 128 + wc + ni * 16 + fr;
            int mbase = ti * 128 + wr + mi * 16 + fq * 4;
#pragma unroll
            for (int j = 0; j < 4; ++j)
                outp[(size_t)(mbase + j) * T + s] = acc[mi][ni][j];
        }
}

// ---------------- sb[h][t][s] = bf16(sum_ks spart), strict causal mask ------
__global__ __launch_bounds__(256) void mask_cvt_k(const float* __restrict__ spart,
                                                  bf16* __restrict__ sb) {
    int t = blockIdx.x, h = blockIdx.y;
    const float* s0 = spart + ((size_t)h * T + t) * T;
    const size_t st = (size_t)H * T * T;
    bf16* o = sb + ((size_t)h * T + t) * T;
#pragma unroll
    for (int s0i = 0; s0i < T; s0i += 256) {
        int s = s0i + threadIdx.x;
        float w = (s < t) ? (s0[s] + s0[st + s] + s0[2 * st + s] + s0[3 * st + s])
                          : 0.0f;
        o[s] = (bf16)w;
    }
}

// ---------------- av: ykv_pre[h][t][d] = sum_s sb[t,s] * x[s,d] (MFMA) ------
__global__ __launch_bounds__(256) void av_mfma_k(const bf16* __restrict__ sb,
                                                 const bf16* __restrict__ xbT,
                                                 float* __restrict__ ykv_pre) {
    __shared__ bf16 As[128][40];
    __shared__ bf16 Bs[128][40];
    int h = blockIdx.z;
    int ti = blockIdx.y;
    int row0 = ti * 128, col0 = blockIdx.x * 128;
    const bf16* Ap = sb + ((size_t)h * T + row0) * T;
    const bf16* Bp = xbT + (size_t)col0 * T;
    int tid = threadIdx.x;
    f32x4 acc[4][4];
#pragma unroll
    for (int i = 0; i < 4; ++i)
#pragma unroll
        for (int j = 0; j < 4; ++j) acc[i][j] = f32x4{0.f, 0.f, 0.f, 0.f};
    // causal: sb[t][s]==0 for s>=t, so only need k < (ti+1)*128
    gemm_core(Ap, T, Bp, T, (ti + 1) * 4, As, Bs, acc, tid);

    int lane = tid & 63, wid = tid >> 6;
    int wr = (wid >> 1) * 64, wc = (wid & 1) * 64;
    int fr = lane & 15, fq = lane >> 4;
#pragma unroll
    for (int mi = 0; mi < 4; ++mi)
#pragma unroll
        for (int ni = 0; ni < 4; ++ni) {
            int n = col0 + wc + ni * 16 + fr;
            int mbase = row0 + wr + mi * 16 + fq * 4;
#pragma unroll
            for (int j = 0; j < 4; ++j)
                ykv_pre[((size_t)h * T + (mbase + j)) * D + n] = acc[mi][ni][j];
        }
}

// ---------------- ykv LN: ykvb = LN(ykv_pre) --------------------------------
__global__ __launch_bounds__(256) void ykv_ln_k(const float* __restrict__ ykv_pre,
                                                bf16* __restrict__ ykvb) {
    __shared__ float red[4];
    int t = blockIdx.x, h = blockIdx.y, d = threadIdx.x;
    float a = ykv_pre[((size_t)h * T + t) * D + d];
    float m = blk_sum256(a, red) * (1.0f / D);
    float df = a - m;
    float vv = blk_sum256(df * df, red) * (1.0f / D);
    ykvb[((size_t)h * T + t) * D + d] = (bf16)(df * rsqrtf(vv + EPSF));
}

// ---------------- decoder GEMM (split-K) ------------------------------------
__global__ __launch_bounds__(256) void dec_mfma_k(const bf16* __restrict__ xyb,
                                                  const bf16* __restrict__ decT,
                                                  float* __restrict__ ypart) {
    __shared__ bf16 As[128][40];
    __shared__ bf16 Bs[128][40];
    int ks = blockIdx.z;
    int cbeg = ks * ((H * NN) / DSPLIT);   // 1024-wide slices, within one head
    int h = cbeg >> 13, n0 = cbeg & (NN - 1);
    int row0 = blockIdx.y * 128, col0 = blockIdx.x * 128;
    const bf16* Ap = xyb + ((size_t)h * T + row0) * NN + n0;
    const bf16* Bp = decT + (size_t)col0 * (H * NN) + cbeg;
    int tid = threadIdx.x;
    f32x4 acc[4][4];
#pragma unroll
    for (int i = 0; i < 4; ++i)
#pragma unroll
        for (int j = 0; j < 4; ++j) acc[i][j] = f32x4{0.f, 0.f, 0.f, 0.f};
    gemm_core(Ap, NN, Bp, H * NN, (H * NN / DSPLIT) / 32, As, Bs, acc, tid);

    int lane = tid & 63, wid = tid >> 6;
    int wr = (wid >> 1) * 64, wc = (wid & 1) * 64;
    int fr = lane & 15, fq = lane >> 4;
#pragma unroll
    for (int mi = 0; mi < 4; ++mi)
#pragma unroll
        for (int ni = 0; ni < 4; ++ni) {
            int n = col0 + wc + ni * 16 + fr;
            int mbase = row0 + wr + mi * 16 + fq * 4;
#pragma unroll
            for (int j = 0; j < 4; ++j)
                ypart[((size_t)ks * T + (mbase + j)) * D + n] = acc[mi][ni][j];
        }
}

// ---------------- y = LN(sum ypart); x = LN(x + y); bf16 + bf16^T copies ----
__global__ __launch_bounds__(256) void final_ln_k(const float* __restrict__ ypart,
                                                  float* __restrict__ x,
                                                  bf16* __restrict__ xb,
                                                  bf16* __restrict__ xbT) {
    __shared__ float red[4];
    int t = blockIdx.x, d = threadIdx.x;
    float ys = 0.0f;
#pragma unroll
    for (int ks = 0; ks < DSPLIT; ++ks) ys += ypart[((size_t)ks * T + t) * D + d];
    float m = blk_sum256(ys, red) * (1.0f / D);
    float df = ys - m;
    float vv = blk_sum256(df * df, red) * (1.0f / D);
    float yln = df * rsqrtf(vv + EPSF);
    float val = x[(size_t)t * D + d] + yln;
    float m2 = blk_sum256(val, red) * (1.0f / D);
    float df2 = val - m2;
    float v2 = blk_sum256(df2 * df2, red) * (1.0f / D);
    float r = df2 * rsqrtf(v2 + EPSF);
    x[(size_t)t * D + d] = r;
    xb[(size_t)t * D + d] = (bf16)r;
    xbT[(size_t)d * T + t] = (bf16)r;
}

// ---------------- logits = x @ lm_head (f32) --------------------------------
__global__ __launch_bounds__(256) void logits_k(const float* __restrict__ x,
                                                const float* __restrict__ lm,
                                                float* __restrict__ out) {
    int t = blockIdx.x, v = threadIdx.x;
    float a = 0.0f;
    for (int d = 0; d < D; ++d)
        a = fmaf(x[(size_t)t * D + d], lm[(size_t)d * V + v], a);
    out[(size_t)t * V + v] = a;
}

extern "C" void kernel_launch(void* const* d_in, const int* in_sizes, int n_in,
                              void* d_out, int out_size, void* d_ws, size_t ws_size,
                              hipStream_t stream) {
    const int*   idx       = (const int*)d_in[0];
    const float* embed     = (const float*)d_in[1];
    const float* encoder   = (const float*)d_in[2];
    const float* encoder_v = (const float*)d_in[3];
    const float* decoder   = (const float*)d_in[4];
    const float* lm_head   = (const float*)d_in[5];
    float* out = (float*)d_out;

    // ---- workspace layout ----
    char* W = (char*)d_ws;
    float* x       = (float*)W; W += (size_t)T * D * 4;
    float* scratch = (float*)W; W += (size_t)QKS * H * T * T * 4;  // spart / ykv_pre / ypart union
    bf16* xb    = (bf16*)W; W += (size_t)T * D * 2;
    bf16* xbT   = (bf16*)W; W += (size_t)D * T * 2;
    bf16* sb    = (bf16*)W; W += (size_t)H * T * T * 2;
    bf16* ykvb  = (bf16*)W; W += (size_t)H * T * D * 2;
    bf16* encT  = (bf16*)W; W += (size_t)H * NN * D * 2;
    bf16* encVT = (bf16*)W; W += (size_t)H * NN * D * 2;
    bf16* decT  = (bf16*)W; W += (size_t)D * H * NN * 2;
    bf16* cosT  = (bf16*)W; W += (size_t)T * NN * 2;
    bf16* sinT  = (bf16*)W; W += (size_t)T * NN * 2;
    bf16* xs    = (bf16*)W; W += (size_t)H * T * NN * 2;
    bf16* qr    = (bf16*)W; W += (size_t)H * T * NN * 2;

    // ---- one-time per launch: weight transpose+convert, RoPE tables ----
    tcvt_k<<<dim3(NN / 32, D / 32, H), 256, 0, stream>>>(encoder, encT, D, NN);
    tcvt_k<<<dim3(NN / 32, D / 32, H), 256, 0, stream>>>(encoder_v, encVT, D, NN);
    tcvt_k<<<dim3(D / 32, (H * NN) / 32, 1), 256, 0, stream>>>(decoder, decT, H * NN, D);
    rope_tab_k<<<dim3(NN / 256, T), 256, 0, stream>>>(cosT, sinT);

    embed_ln_k<<<T, 256, 0, stream>>>(idx, embed, x, xb, xbT);

    for (int layer = 0; layer < N_LAYER; ++layer) {
        enc_mfma_k<0><<<dim3(NN / 128, T / 128, H), 256, 0, stream>>>(
            xb, encT, xs, qr, cosT, sinT, 0);
        qq_mfma_k<<<dim3(10, H, QKS), 256, 0, stream>>>(qr, scratch);
        mask_cvt_k<<<dim3(T, H), 256, 0, stream>>>(scratch, sb);
        av_mfma_k<<<dim3(D / 128, T / 128, H), 256, 0, stream>>>(sb, xbT, scratch);
        ykv_ln_k<<<dim3(T, H), 256, 0, stream>>>(scratch, ykvb);
        enc_mfma_k<1><<<dim3(NN / 128, T / 128, H), 256, 0, stream>>>(
            ykvb, encVT, xs, nullptr, nullptr, nullptr, T * D);
        dec_mfma_k<<<dim3(D / 128, T / 128, DSPLIT), 256, 0, stream>>>(
            xs, decT, scratch);
        final_ln_k<<<T, 256, 0, stream>>>(scratch, x, xb, xbT);
    }

    logits_k<<<T, 256, 0, stream>>>(x, lm_head, out);
}